// Round 12
// baseline (675.427 us; speedup 1.0000x reference)
//
#include <hip/hip_runtime.h>
#include <hip/hip_bf16.h>

// VQ EuclideanCodebook round 12: SINGLE-sweep MFMA filter with in-register
// online top-3 (values)/top-2 (indices) per row; provable candidate capture
// via acc-domain margin; fused re-rank (c==2 fixed) + count-sort epilogue.

#define NROWS 262144
#define KCODES 1024
#define DDIM 64

typedef __attribute__((ext_vector_type(8))) short short8;
typedef __attribute__((ext_vector_type(4))) float f32x4;
typedef __attribute__((ext_vector_type(4))) int   i32x4;

__device__ __forceinline__ unsigned short f2bf(float f) {
    unsigned u = __float_as_uint(f);
    unsigned r = u + 0x7fffu + ((u >> 16) & 1u);   // RNE to bf16
    return (unsigned short)(r >> 16);
}

// ---- prep: e2 (exact f32), E->bf16 PRE-SWIZZLED, max ||e||^2 ----
__global__ __launch_bounds__(256) void vq_prep(
    const float* __restrict__ embed, unsigned short* __restrict__ eb,
    float* __restrict__ e2f, float* __restrict__ enmax2)
{
    const int k = blockIdx.x * 256 + threadIdx.x;   // 0..1023
    const float* er = embed + (size_t)k * DDIM;
    float s = 0.f;
    #pragma unroll
    for (int d = 0; d < DDIM; ++d) { float v = er[d]; s = fmaf(v, v, s); }
    e2f[k] = s;
    unsigned char* base = (unsigned char*)eb + (k >> 8) * 32768 +
                          ((k >> 5) & 7) * 4096 + (k & 31) * 128;
    #pragma unroll
    for (int sl = 0; sl < 8; ++sl) {
        short8 f;
        #pragma unroll
        for (int j = 0; j < 8; ++j) f[j] = (short)f2bf(er[sl * 8 + j]);
        *reinterpret_cast<short8*>(base + ((sl ^ (k & 7)) << 4)) = f;
    }
    atomicMax((int*)enmax2, __float_as_int(s));     // s >= 0: int-monotone
}

// branchless top-3 values / top-2 indices update
#define T3U(v, idx, V1, I1, V2, I2, V3)                                       \
    {                                                                         \
        const bool g1 = (v) > (V1);                                           \
        const bool g2 = (v) > (V2);                                           \
        const bool g3 = (v) > (V3);                                           \
        (V3) = g2 ? (V2) : (g3 ? (v) : (V3));                                 \
        (V2) = g1 ? (V1) : (g2 ? (v) : (V2));                                 \
        (I2) = g1 ? (I1) : (g2 ? (idx) : (I2));                               \
        (V1) = g1 ? (v) : (V1);                                               \
        (I1) = g1 ? (idx) : (I1);                                             \
    }

// ---- phase A: single sweep, online top-3, double-buffered quarters ----
__global__ __launch_bounds__(512) void vq_phaseA(
    const float* __restrict__ x, const unsigned short* __restrict__ eb,
    const float* __restrict__ e2f, const float* __restrict__ enmax2,
    float* __restrict__ out_ind, int* __restrict__ candg,
    int* __restrict__ wl, int* __restrict__ gcount,
    int* __restrict__ wl2, int* __restrict__ gcount2, int* __restrict__ bins_i)
{
    __shared__ __align__(16) unsigned short ebs0[16384];  // 32 KB quarter buf A
    __shared__ __align__(16) unsigned short ebs1[16384];  // 32 KB quarter buf B
    __shared__ float e2L[KCODES];     // -0.5*e2
    __shared__ float norm2L[256];
    __shared__ int   cntL[256];
    __shared__ int   candL[256][2];
    __shared__ int   mcount, mbase, mcount2, mbase2;

    const int t    = threadIdx.x;
    const int lane = t & 63;
    const int wid  = t >> 6;          // 8 waves, 32 rows each
    const int col  = lane & 15;
    const int q    = lane >> 4;       // 0..3
    const int rowb = blockIdx.x * 256;
    const int r0   = wid * 32;

#define STAGEQ(BUF, P)                                                        \
    {                                                                         \
        const unsigned char* gsrc = (const unsigned char*)eb +                \
            (size_t)(P) * 32768 + t * 16;                                     \
        unsigned char* ldst = (unsigned char*)(BUF) + t * 16;                 \
        _Pragma("unroll")                                                     \
        for (int it = 0; it < 4; ++it)                                        \
            __builtin_amdgcn_global_load_lds(                                 \
                (const __attribute__((address_space(1))) void*)(gsrc + it * 8192), \
                (__attribute__((address_space(3))) void*)(ldst + it * 8192),  \
                16, 0, 0);                                                    \
    }

    STAGEQ(ebs0, 0)

    // A fragments (row=lane&15, k = m*32 + 8*q + j) for 2 tiles + row norms
    short8 a0[2], a1[2];
    {
        const float* xr = x + (size_t)(rowb + r0 + col) * DDIM;
        float s = 0.f;
        #pragma unroll
        for (int m = 0; m < 2; ++m) {
            const float4 u = *reinterpret_cast<const float4*>(xr + m * 32 + 8 * q);
            const float4 v = *reinterpret_cast<const float4*>(xr + m * 32 + 8 * q + 4);
            short8 f;
            f[0] = (short)f2bf(u.x); f[1] = (short)f2bf(u.y);
            f[2] = (short)f2bf(u.z); f[3] = (short)f2bf(u.w);
            f[4] = (short)f2bf(v.x); f[5] = (short)f2bf(v.y);
            f[6] = (short)f2bf(v.z); f[7] = (short)f2bf(v.w);
            a0[m] = f;
            s = fmaf(u.x, u.x, s); s = fmaf(u.y, u.y, s);
            s = fmaf(u.z, u.z, s); s = fmaf(u.w, u.w, s);
            s = fmaf(v.x, v.x, s); s = fmaf(v.y, v.y, s);
            s = fmaf(v.z, v.z, s); s = fmaf(v.w, v.w, s);
        }
        s += __shfl_xor(s, 16); s += __shfl_xor(s, 32);
        if (lane < 16) norm2L[r0 + lane] = s;
    }
    {
        const float* xr = x + (size_t)(rowb + r0 + 16 + col) * DDIM;
        float s = 0.f;
        #pragma unroll
        for (int m = 0; m < 2; ++m) {
            const float4 u = *reinterpret_cast<const float4*>(xr + m * 32 + 8 * q);
            const float4 v = *reinterpret_cast<const float4*>(xr + m * 32 + 8 * q + 4);
            short8 f;
            f[0] = (short)f2bf(u.x); f[1] = (short)f2bf(u.y);
            f[2] = (short)f2bf(u.z); f[3] = (short)f2bf(u.w);
            f[4] = (short)f2bf(v.x); f[5] = (short)f2bf(v.y);
            f[6] = (short)f2bf(v.z); f[7] = (short)f2bf(v.w);
            a1[m] = f;
            s = fmaf(u.x, u.x, s); s = fmaf(u.y, u.y, s);
            s = fmaf(u.z, u.z, s); s = fmaf(u.w, u.w, s);
            s = fmaf(v.x, v.x, s); s = fmaf(v.y, v.y, s);
            s = fmaf(v.z, v.z, s); s = fmaf(v.w, v.w, s);
        }
        s += __shfl_xor(s, 16); s += __shfl_xor(s, 32);
        if (lane < 16) norm2L[r0 + 16 + lane] = s;
    }

    e2L[t]       = -0.5f * e2f[t];
    e2L[512 + t] = -0.5f * e2f[512 + t];
    if (t == 0) { mcount = 0; mcount2 = 0; }
    const float en2 = *enmax2;

    const int off0 = col * 128 + ((q       ^ (col & 7)) << 4);
    const int off1 = col * 128 + (((4 + q) ^ (col & 7)) << 4);

    // top-3 state (static indices only)
    f32x4 v1a, v2a, v3a, v1b, v2b, v3b;
    i32x4 i1a, i2a, i1b, i2b;
    #pragma unroll
    for (int r = 0; r < 4; ++r) {
        v1a[r] = -3.4e38f; v2a[r] = -3.4e38f; v3a[r] = -3.4e38f;
        v1b[r] = -3.4e38f; v2b[r] = -3.4e38f; v3b[r] = -3.4e38f;
        i1a[r] = 0; i2a[r] = 0; i1b[r] = 0; i2b[r] = 0;
    }

#define CHUNKS(BUF, P)                                                        \
    _Pragma("unroll 4")                                                       \
    for (int ch = 0; ch < 16; ++ch) {                                         \
        const short8 b0 = *reinterpret_cast<const short8*>(                   \
            (char*)(BUF) + ch * 2048 + off0);                                 \
        const short8 b1 = *reinterpret_cast<const short8*>(                   \
            (char*)(BUF) + ch * 2048 + off1);                                 \
        const float e2n = e2L[(P) * 256 + ch * 16 + col];                     \
        f32x4 acc0, acc1;                                                     \
        acc0[0] = e2n; acc0[1] = e2n; acc0[2] = e2n; acc0[3] = e2n;           \
        acc1 = acc0;                                                          \
        acc0 = __builtin_amdgcn_mfma_f32_16x16x32_bf16(a0[0], b0, acc0, 0, 0, 0); \
        acc1 = __builtin_amdgcn_mfma_f32_16x16x32_bf16(a1[0], b0, acc1, 0, 0, 0); \
        acc0 = __builtin_amdgcn_mfma_f32_16x16x32_bf16(a0[1], b1, acc0, 0, 0, 0); \
        acc1 = __builtin_amdgcn_mfma_f32_16x16x32_bf16(a1[1], b1, acc1, 0, 0, 0); \
        const int idx = (P) * 256 + ch * 16 + col;                            \
        _Pragma("unroll")                                                     \
        for (int r = 0; r < 4; ++r) {                                         \
            T3U(acc0[r], idx, v1a[r], i1a[r], v2a[r], i2a[r], v3a[r])         \
            T3U(acc1[r], idx, v1b[r], i1b[r], v2b[r], i2b[r], v3b[r])         \
        }                                                                     \
    }

    // ---------- the single sweep (prefetch next quarter before compute) ----
    __syncthreads();                       // quarter 0 resident
    STAGEQ(ebs1, 1)  CHUNKS(ebs0, 0)  __syncthreads();
    STAGEQ(ebs0, 2)  CHUNKS(ebs1, 1)  __syncthreads();
    STAGEQ(ebs1, 3)  CHUNKS(ebs0, 2)  __syncthreads();
    CHUNKS(ebs1, 3)

    // ---------- cross-lane top-3 merge + per-row decision ----------
    #pragma unroll
    for (int tile = 0; tile < 2; ++tile) {
        #pragma unroll
        for (int r = 0; r < 4; ++r) {
            float a1v = tile ? v1b[r] : v1a[r];
            float a2v = tile ? v2b[r] : v2a[r];
            float a3v = tile ? v3b[r] : v3a[r];
            int   b1v = tile ? i1b[r] : i1a[r];
            int   b2v = tile ? i2b[r] : i2a[r];
            #pragma unroll
            for (int s = 1; s < 16; s <<= 1) {
                const float w1 = __shfl_xor(a1v, s);
                const float w2 = __shfl_xor(a2v, s);
                const float w3 = __shfl_xor(a3v, s);
                const int   j1 = __shfl_xor(b1v, s);
                const int   j2 = __shfl_xor(b2v, s);
                float n1, n2, n3; int m1, m2;
                if (a1v >= w1) {
                    n1 = a1v; m1 = b1v;
                    if (a2v >= w1) { n2 = a2v; m2 = b2v; n3 = fmaxf(a3v, w1); }
                    else           { n2 = w1;  m2 = j1;  n3 = fmaxf(a2v, w2); }
                } else {
                    n1 = w1; m1 = j1;
                    if (w2 >= a1v) { n2 = w2;  m2 = j2;  n3 = fmaxf(w3, a1v); }
                    else           { n2 = a1v; m2 = b1v; n3 = fmaxf(w2, a2v); }
                }
                a1v = n1; a2v = n2; a3v = n3; b1v = m1; b2v = m2;
            }
            if (col == 0) {
                const int rl = r0 + tile * 16 + q * 4 + r;
                const float m = 0.0078125f * sqrtf(norm2L[rl] * en2) + 5e-5f;
                const float thr = a1v - m;
                cntL[rl] = (a2v < thr) ? 1 : ((a3v < thr) ? 2 : 8);
                candL[rl][0] = b1v; candL[rl][1] = b2v;
            }
        }
    }
    __syncthreads();

    // finalize single-candidate rows (+histogram); enqueue pair/overflow rows
    int my = -1, my2 = -1;
    if (t < 256) {
        const int c = cntL[t];
        if (c == 1) {
            const int code = candL[t][0];
            out_ind[rowb + t] = (float)code;
            atomicAdd(bins_i + code, 1);
        }
        else if (c == 2)   my  = atomicAdd(&mcount, 1);
        else               my2 = atomicAdd(&mcount2, 1);
    }
    __syncthreads();
    if (t == 0) { mbase = atomicAdd(gcount, mcount); mbase2 = atomicAdd(gcount2, mcount2); }
    __syncthreads();
    if (my >= 0) {
        const int row = rowb + t;
        wl[mbase + my] = row;
        candg[row * 2 + 0] = candL[t][0];
        candg[row * 2 + 1] = candL[t][1];
    }
    if (my2 >= 0) wl2[mbase2 + my2] = rowb + t;
#undef STAGEQ
#undef CHUNKS
}

// ---- fused re-rank: thread-per-row (exactly 2 cands) + wave overflow ----
__global__ __launch_bounds__(256) void vq_rerank(
    const float* __restrict__ x, const float* __restrict__ embed,
    const float* __restrict__ e2f, const int* __restrict__ wl,
    const int* __restrict__ gcount, const int* __restrict__ candg,
    const int* __restrict__ wl2, const int* __restrict__ gcount2,
    float* __restrict__ out_ind, int* __restrict__ bins_i)
{
    const int t = threadIdx.x;
    const int n = *gcount;
    for (int i = blockIdx.x * 256 + t; i < n; i += gridDim.x * 256) {
        const int row = wl[i];
        const int k0 = candg[row * 2 + 0];
        const int k1 = candg[row * 2 + 1];
        const float4* xp  = reinterpret_cast<const float4*>(x + (size_t)row * DDIM);
        const float4* ep0 = reinterpret_cast<const float4*>(embed + (size_t)k0 * DDIM);
        const float4* ep1 = reinterpret_cast<const float4*>(embed + (size_t)k1 * DDIM);
        float x2 = 0.f, dot0 = 0.f, dot1 = 0.f;
        #pragma unroll
        for (int qq = 0; qq < 16; ++qq) {
            const float4 xv = xp[qq];
            const float4 e0 = ep0[qq];
            const float4 e1 = ep1[qq];
            x2   = fmaf(xv.x, xv.x, x2);   x2   = fmaf(xv.y, xv.y, x2);
            x2   = fmaf(xv.z, xv.z, x2);   x2   = fmaf(xv.w, xv.w, x2);
            dot0 = fmaf(xv.x, e0.x, dot0); dot0 = fmaf(xv.y, e0.y, dot0);
            dot0 = fmaf(xv.z, e0.z, dot0); dot0 = fmaf(xv.w, e0.w, dot0);
            dot1 = fmaf(xv.x, e1.x, dot1); dot1 = fmaf(xv.y, e1.y, dot1);
            dot1 = fmaf(xv.z, e1.z, dot1); dot1 = fmaf(xv.w, e1.w, dot1);
        }
        const float d0 = (x2 - 2.0f * dot0) + e2f[k0];
        const float d1 = (x2 - 2.0f * dot1) + e2f[k1];
        int bk = k0;
        if (d1 < d0 || (d1 == d0 && k1 < k0)) bk = k1;
        out_ind[row] = (float)bk;
        atomicAdd(bins_i + bk, 1);
    }

    // overflow rows: exact full scan, one wave per row
    const int lane = t & 63;
    const int gw   = (blockIdx.x * 256 + t) >> 6;
    const int nw   = (gridDim.x * 256) >> 6;
    const int n2   = *gcount2;
    for (int e = gw; e < n2; e += nw) {
        const int row = wl2[e];
        float xv[DDIM];
        {
            const float4* xp = reinterpret_cast<const float4*>(x + (size_t)row * DDIM);
            #pragma unroll
            for (int qq = 0; qq < 16; ++qq) {
                const float4 v = xp[qq];
                xv[qq*4+0] = v.x; xv[qq*4+1] = v.y; xv[qq*4+2] = v.z; xv[qq*4+3] = v.w;
            }
        }
        float x2 = 0.f;
        #pragma unroll
        for (int d = 0; d < DDIM; ++d) x2 = fmaf(xv[d], xv[d], x2);

        float bv = 3.4e38f; int bk = 0x7fffffff;
        for (int k = lane; k < KCODES; k += 64) {
            const float* er = embed + (size_t)k * DDIM;
            float dot = 0.f;
            #pragma unroll
            for (int d = 0; d < DDIM; ++d) dot = fmaf(xv[d], er[d], dot);
            const float dist = (x2 - 2.0f * dot) + e2f[k];
            if (dist < bv) { bv = dist; bk = k; }
        }
        #pragma unroll
        for (int s = 1; s < 64; s <<= 1) {
            const float ov = __shfl_xor(bv, s);
            const int   ok = __shfl_xor(bk, s);
            if (ov < bv || (ov == bv && ok < bk)) { bv = ov; bk = ok; }
        }
        if (lane == 0) { out_ind[row] = (float)bk; atomicAdd(bins_i + bk, 1); }
    }
}

// ---- exclusive prefix over bins -> cursor ----
__global__ __launch_bounds__(1024) void vq_prefix(
    const int* __restrict__ bins_i, int* __restrict__ cursor)
{
    __shared__ int s[KCODES];
    const int t = threadIdx.x;
    const int b = bins_i[t];
    s[t] = b;
    __syncthreads();
    for (int d = 1; d < KCODES; d <<= 1) {
        const int v = (t >= d) ? s[t - d] : 0;
        __syncthreads();
        s[t] += v;
        __syncthreads();
    }
    cursor[t] = s[t] - b;
}

// ---- scatter packed (code<<20)|row into code-sorted order ----
__global__ __launch_bounds__(256) void vq_scatter(
    const float* __restrict__ out_ind, int* __restrict__ cursor, int* __restrict__ sorted)
{
    const int row  = blockIdx.x * 256 + threadIdx.x;
    const int code = (int)out_ind[row];
    const int pos  = atomicAdd(cursor + code, 1);
    sorted[pos] = (code << 20) | row;
}

// ---- balanced segmented reduce: 64 positions per wave, boundary atomics ----
__global__ __launch_bounds__(256) void vq_reduce(
    const float* __restrict__ x, const int* __restrict__ sorted,
    float* __restrict__ esum)
{
    const int t = threadIdx.x, lane = t & 63, w = t >> 6;
    const int p0 = (blockIdx.x * 4 + w) * 64;     // this wave's 64 positions

    int cur = sorted[p0] >> 20;
    float acc = 0.f;
    #pragma unroll 4
    for (int i = 0; i < 64; i += 4) {
        const int4 e4 = *reinterpret_cast<const int4*>(sorted + p0 + i);
        const float v0 = x[(size_t)(e4.x & 0xFFFFF) * DDIM + lane];
        const float v1 = x[(size_t)(e4.y & 0xFFFFF) * DDIM + lane];
        const float v2 = x[(size_t)(e4.z & 0xFFFFF) * DDIM + lane];
        const float v3 = x[(size_t)(e4.w & 0xFFFFF) * DDIM + lane];
        const int c0 = e4.x >> 20, c1 = e4.y >> 20, c2 = e4.z >> 20, c3 = e4.w >> 20;
        if (c0 != cur) { unsafeAtomicAdd(esum + cur * DDIM + lane, acc); acc = 0.f; cur = c0; }
        acc += v0;
        if (c1 != cur) { unsafeAtomicAdd(esum + cur * DDIM + lane, acc); acc = 0.f; cur = c1; }
        acc += v1;
        if (c2 != cur) { unsafeAtomicAdd(esum + cur * DDIM + lane, acc); acc = 0.f; cur = c2; }
        acc += v2;
        if (c3 != cur) { unsafeAtomicAdd(esum + cur * DDIM + lane, acc); acc = 0.f; cur = c3; }
        acc += v3;
    }
    unsafeAtomicAdd(esum + cur * DDIM + lane, acc);
}

// ---- finalize: EMA + Laplace smoothing ----
__global__ __launch_bounds__(1024) void vq_finalize(
    const float* __restrict__ cluster_size, const float* __restrict__ embed_avg,
    const int* __restrict__ bins_i, float* __restrict__ out_cs,
    float* __restrict__ out_eavg, float* __restrict__ out_enorm)
{
    __shared__ float red[KCODES];
    __shared__ float css[KCODES];
    const int t = threadIdx.x;

    const float csn = cluster_size[t] * 0.1f + (float)bins_i[t] * 0.9f;
    red[t] = csn;
    __syncthreads();
    for (int s = 512; s > 0; s >>= 1) {
        if (t < s) red[t] += red[t + s];
        __syncthreads();
    }
    const float n = red[0];
    out_cs[t] = csn;
    css[t] = (csn + 1e-5f) / (n + (float)(KCODES * 1e-5)) * n;
    __syncthreads();

    #pragma unroll
    for (int i = 0; i < 16; ++i) {
        const int f4 = t + i * 1024;
        const int k  = f4 >> 4;
        const float4 ea = reinterpret_cast<const float4*>(embed_avg)[f4];
        const float4 su = reinterpret_cast<const float4*>(out_eavg)[f4];
        const float  cc = css[k];
        float4 ean, en;
        ean.x = ea.x * 0.1f + su.x * 0.9f; en.x = ean.x / cc;
        ean.y = ea.y * 0.1f + su.y * 0.9f; en.y = ean.y / cc;
        ean.z = ea.z * 0.1f + su.z * 0.9f; en.z = ean.z / cc;
        ean.w = ea.w * 0.1f + su.w * 0.9f; en.w = ean.w / cc;
        reinterpret_cast<float4*>(out_eavg)[f4]  = ean;
        reinterpret_cast<float4*>(out_enorm)[f4] = en;
    }
}

// ---- quantize gather (runs last; out_q region doubles as scratch before) ----
__global__ __launch_bounds__(256) void vq_quant(
    const float* __restrict__ out_ind, const float* __restrict__ embed,
    float* __restrict__ out_q)
{
    __shared__ int inds[256];
    const int t = threadIdx.x;
    const int row0 = blockIdx.x * 256;
    inds[t] = (int)out_ind[row0 + t];
    __syncthreads();
    #pragma unroll
    for (int i = 0; i < 16; ++i) {
        const int f = t + i * 256;
        const int r = f >> 4, dq = f & 15;
        const int code = inds[r];
        const float4 ev = *reinterpret_cast<const float4*>(
            embed + (size_t)code * DDIM + dq * 4);
        *reinterpret_cast<float4*>(out_q + (size_t)(row0 + r) * DDIM + dq * 4) = ev;
    }
}

extern "C" void kernel_launch(void* const* d_in, const int* in_sizes, int n_in,
                              void* d_out, int out_size, void* d_ws, size_t ws_size,
                              hipStream_t stream)
{
    const float* x            = (const float*)d_in[0];
    const float* embed        = (const float*)d_in[1];
    const float* cluster_size = (const float*)d_in[2];
    const float* embed_avg    = (const float*)d_in[3];

    float* out      = (float*)d_out;
    float* out_q    = out;                                   // N*D (scratch until vq_quant)
    float* out_ind  = out_q + (size_t)NROWS * DDIM;          // N
    float* out_cs   = out_ind + NROWS;                       // K
    float* out_eavg = out_cs + KCODES;                       // K*D (embed_sum accum, then EMA)
    float* out_en   = out_eavg + (size_t)KCODES * DDIM;      // K*D (eb/e2f scratch, then enorm)

    unsigned short* eb = (unsigned short*)out_en;            // K*D bf16 = 128 KB (pre-swizzled)
    float* e2f = out_en + 32768;                             // K floats

    int* S      = (int*)out_q;                               // scratch inside out_q
    int* candg  = S;                                         // N*2
    int* wl     = S + 524288;                                // N
    int* wl2    = wl + 262144;                               // N
    int* sorted = wl2 + 262144;                              // N
    int* bins_i = sorted + 262144;                           // K
    int* gcount = bins_i + KCODES;                           // 1
    int* gcount2= gcount + 1;                                // 1
    float* enmax2 = (float*)(gcount2 + 1);                   // 1
    int* cursor = gcount2 + 2;                               // K

    hipMemsetAsync(bins_i, 0, (KCODES + 3) * sizeof(int), stream);
    hipMemsetAsync(out_eavg, 0, (size_t)KCODES * DDIM * sizeof(float), stream);

    vq_prep    <<<KCODES / 256, 256, 0, stream>>>(embed, eb, e2f, enmax2);
    vq_phaseA  <<<NROWS / 256, 512, 0, stream>>>(x, eb, e2f, enmax2, out_ind,
                                                 candg, wl, gcount,
                                                 wl2, gcount2, bins_i);
    vq_rerank  <<<512, 256, 0, stream>>>(x, embed, e2f, wl, gcount, candg,
                                         wl2, gcount2, out_ind, bins_i);
    vq_prefix  <<<1, 1024, 0, stream>>>(bins_i, cursor);
    vq_scatter <<<NROWS / 256, 256, 0, stream>>>(out_ind, cursor, sorted);
    vq_reduce  <<<NROWS / 256, 256, 0, stream>>>(x, sorted, out_eavg);
    vq_finalize<<<1, 1024, 0, stream>>>(cluster_size, embed_avg, bins_i,
                                        out_cs, out_eavg, out_en);
    vq_quant   <<<NROWS / 256, 256, 0, stream>>>(out_ind, embed, out_q);
}

// Round 13
// 381.137 us; speedup vs baseline: 1.7721x; 1.7721x over previous
//
#include <hip/hip_runtime.h>
#include <hip/hip_bf16.h>

// VQ EuclideanCodebook round 13: single-sweep MFMA filter with per-lane top-3
// + LDS candidate collection (poisoned-count overflow), thread-per-row exact
// re-rank (c<=6), coalesced lane=dim overflow scan, count-sort epilogue.

#define NROWS 262144
#define KCODES 1024
#define DDIM 64
#define CAPL 6

typedef __attribute__((ext_vector_type(8))) short short8;
typedef __attribute__((ext_vector_type(4))) float f32x4;
typedef __attribute__((ext_vector_type(4))) int   i32x4;

__device__ __forceinline__ unsigned short f2bf(float f) {
    unsigned u = __float_as_uint(f);
    unsigned r = u + 0x7fffu + ((u >> 16) & 1u);   // RNE to bf16
    return (unsigned short)(r >> 16);
}

// ---- prep: e2 (exact f32), E->bf16 PRE-SWIZZLED, max ||e||^2 ----
__global__ __launch_bounds__(256) void vq_prep(
    const float* __restrict__ embed, unsigned short* __restrict__ eb,
    float* __restrict__ e2f, float* __restrict__ enmax2)
{
    const int k = blockIdx.x * 256 + threadIdx.x;   // 0..1023
    const float* er = embed + (size_t)k * DDIM;
    float s = 0.f;
    #pragma unroll
    for (int d = 0; d < DDIM; ++d) { float v = er[d]; s = fmaf(v, v, s); }
    e2f[k] = s;
    unsigned char* base = (unsigned char*)eb + (k >> 8) * 32768 +
                          ((k >> 5) & 7) * 4096 + (k & 31) * 128;
    #pragma unroll
    for (int sl = 0; sl < 8; ++sl) {
        short8 f;
        #pragma unroll
        for (int j = 0; j < 8; ++j) f[j] = (short)f2bf(er[sl * 8 + j]);
        *reinterpret_cast<short8*>(base + ((sl ^ (k & 7)) << 4)) = f;
    }
    atomicMax((int*)enmax2, __float_as_int(s));     // s >= 0: int-monotone
}

// branchless top-3 values / top-2 indices update
#define T3U(v, idx, V1, I1, V2, I2, V3)                                       \
    {                                                                         \
        const bool g1 = (v) > (V1);                                           \
        const bool g2 = (v) > (V2);                                           \
        const bool g3 = (v) > (V3);                                           \
        (V3) = g2 ? (V2) : (g3 ? (v) : (V3));                                 \
        (V2) = g1 ? (V1) : (g2 ? (v) : (V2));                                 \
        (I2) = g1 ? (I1) : (g2 ? (idx) : (I2));                               \
        (V1) = g1 ? (v) : (V1);                                               \
        (I1) = g1 ? (idx) : (I1);                                             \
    }

// ---- phase A: single sweep, per-lane top-3, LDS candidate collection ----
__global__ __launch_bounds__(512) void vq_phaseA(
    const float* __restrict__ x, const unsigned short* __restrict__ eb,
    const float* __restrict__ e2f, const float* __restrict__ enmax2,
    float* __restrict__ out_ind, int* __restrict__ candg, int* __restrict__ cntg,
    int* __restrict__ wl, int* __restrict__ gcount,
    int* __restrict__ wl2, int* __restrict__ gcount2, int* __restrict__ bins_i)
{
    __shared__ __align__(16) unsigned short ebs0[16384];  // 32 KB quarter buf A
    __shared__ __align__(16) unsigned short ebs1[16384];  // 32 KB quarter buf B
    __shared__ float e2L[KCODES];     // -0.5*e2
    __shared__ float norm2L[256];
    __shared__ int   cntL[256];
    __shared__ int   candL[256][CAPL];
    __shared__ int   mcount, mbase, mcount2, mbase2;

    const int t    = threadIdx.x;
    const int lane = t & 63;
    const int wid  = t >> 6;          // 8 waves, 32 rows each
    const int col  = lane & 15;
    const int q    = lane >> 4;       // 0..3
    const int rowb = blockIdx.x * 256;
    const int r0   = wid * 32;

#define STAGEQ(BUF, P)                                                        \
    {                                                                         \
        const unsigned char* gsrc = (const unsigned char*)eb +                \
            (size_t)(P) * 32768 + t * 16;                                     \
        unsigned char* ldst = (unsigned char*)(BUF) + t * 16;                 \
        _Pragma("unroll")                                                     \
        for (int it = 0; it < 4; ++it)                                        \
            __builtin_amdgcn_global_load_lds(                                 \
                (const __attribute__((address_space(1))) void*)(gsrc + it * 8192), \
                (__attribute__((address_space(3))) void*)(ldst + it * 8192),  \
                16, 0, 0);                                                    \
    }

    STAGEQ(ebs0, 0)

    // A fragments (row=lane&15, k = m*32 + 8*q + j) for 2 tiles + row norms
    short8 a0[2], a1[2];
    {
        const float* xr = x + (size_t)(rowb + r0 + col) * DDIM;
        float s = 0.f;
        #pragma unroll
        for (int m = 0; m < 2; ++m) {
            const float4 u = *reinterpret_cast<const float4*>(xr + m * 32 + 8 * q);
            const float4 v = *reinterpret_cast<const float4*>(xr + m * 32 + 8 * q + 4);
            short8 f;
            f[0] = (short)f2bf(u.x); f[1] = (short)f2bf(u.y);
            f[2] = (short)f2bf(u.z); f[3] = (short)f2bf(u.w);
            f[4] = (short)f2bf(v.x); f[5] = (short)f2bf(v.y);
            f[6] = (short)f2bf(v.z); f[7] = (short)f2bf(v.w);
            a0[m] = f;
            s = fmaf(u.x, u.x, s); s = fmaf(u.y, u.y, s);
            s = fmaf(u.z, u.z, s); s = fmaf(u.w, u.w, s);
            s = fmaf(v.x, v.x, s); s = fmaf(v.y, v.y, s);
            s = fmaf(v.z, v.z, s); s = fmaf(v.w, v.w, s);
        }
        s += __shfl_xor(s, 16); s += __shfl_xor(s, 32);
        if (lane < 16) norm2L[r0 + lane] = s;
    }
    {
        const float* xr = x + (size_t)(rowb + r0 + 16 + col) * DDIM;
        float s = 0.f;
        #pragma unroll
        for (int m = 0; m < 2; ++m) {
            const float4 u = *reinterpret_cast<const float4*>(xr + m * 32 + 8 * q);
            const float4 v = *reinterpret_cast<const float4*>(xr + m * 32 + 8 * q + 4);
            short8 f;
            f[0] = (short)f2bf(u.x); f[1] = (short)f2bf(u.y);
            f[2] = (short)f2bf(u.z); f[3] = (short)f2bf(u.w);
            f[4] = (short)f2bf(v.x); f[5] = (short)f2bf(v.y);
            f[6] = (short)f2bf(v.z); f[7] = (short)f2bf(v.w);
            a1[m] = f;
            s = fmaf(u.x, u.x, s); s = fmaf(u.y, u.y, s);
            s = fmaf(u.z, u.z, s); s = fmaf(u.w, u.w, s);
            s = fmaf(v.x, v.x, s); s = fmaf(v.y, v.y, s);
            s = fmaf(v.z, v.z, s); s = fmaf(v.w, v.w, s);
        }
        s += __shfl_xor(s, 16); s += __shfl_xor(s, 32);
        if (lane < 16) norm2L[r0 + 16 + lane] = s;
    }

    e2L[t]       = -0.5f * e2f[t];
    e2L[512 + t] = -0.5f * e2f[512 + t];
    if (t < 256) cntL[t] = 0;
    if (t == 0) { mcount = 0; mcount2 = 0; }
    const float en2 = *enmax2;

    const int off0 = col * 128 + ((q       ^ (col & 7)) << 4);
    const int off1 = col * 128 + (((4 + q) ^ (col & 7)) << 4);

    // per-lane top-3 values / top-2 indices (static indices only)
    f32x4 v1a, v2a, v3a, v1b, v2b, v3b;
    i32x4 i1a, i2a, i1b, i2b;
    #pragma unroll
    for (int r = 0; r < 4; ++r) {
        v1a[r] = -3.4e38f; v2a[r] = -3.4e38f; v3a[r] = -3.4e38f;
        v1b[r] = -3.4e38f; v2b[r] = -3.4e38f; v3b[r] = -3.4e38f;
        i1a[r] = 0; i2a[r] = 0; i1b[r] = 0; i2b[r] = 0;
    }

#define CHUNKS(BUF, P)                                                        \
    _Pragma("unroll 4")                                                       \
    for (int ch = 0; ch < 16; ++ch) {                                         \
        const short8 b0 = *reinterpret_cast<const short8*>(                   \
            (char*)(BUF) + ch * 2048 + off0);                                 \
        const short8 b1 = *reinterpret_cast<const short8*>(                   \
            (char*)(BUF) + ch * 2048 + off1);                                 \
        const float e2n = e2L[(P) * 256 + ch * 16 + col];                     \
        f32x4 acc0, acc1;                                                     \
        acc0[0] = e2n; acc0[1] = e2n; acc0[2] = e2n; acc0[3] = e2n;           \
        acc1 = acc0;                                                          \
        acc0 = __builtin_amdgcn_mfma_f32_16x16x32_bf16(a0[0], b0, acc0, 0, 0, 0); \
        acc1 = __builtin_amdgcn_mfma_f32_16x16x32_bf16(a1[0], b0, acc1, 0, 0, 0); \
        acc0 = __builtin_amdgcn_mfma_f32_16x16x32_bf16(a0[1], b1, acc0, 0, 0, 0); \
        acc1 = __builtin_amdgcn_mfma_f32_16x16x32_bf16(a1[1], b1, acc1, 0, 0, 0); \
        const int idx = (P) * 256 + ch * 16 + col;                            \
        _Pragma("unroll")                                                     \
        for (int r = 0; r < 4; ++r) {                                         \
            T3U(acc0[r], idx, v1a[r], i1a[r], v2a[r], i2a[r], v3a[r])         \
            T3U(acc1[r], idx, v1b[r], i1b[r], v2b[r], i2b[r], v3b[r])         \
        }                                                                     \
    }

    // ---------- the single sweep (prefetch next quarter before compute) ----
    __syncthreads();                       // quarter 0 resident
    STAGEQ(ebs1, 1)  CHUNKS(ebs0, 0)  __syncthreads();
    STAGEQ(ebs0, 2)  CHUNKS(ebs1, 1)  __syncthreads();
    STAGEQ(ebs1, 3)  CHUNKS(ebs0, 2)  __syncthreads();
    CHUNKS(ebs1, 3)

    // ---------- cross-lane max -> threshold -> per-lane collection ----------
    #pragma unroll
    for (int tile = 0; tile < 2; ++tile) {
        #pragma unroll
        for (int r = 0; r < 4; ++r) {
            float am = tile ? v1b[r] : v1a[r];
            am = fmaxf(am, __shfl_xor(am, 1));
            am = fmaxf(am, __shfl_xor(am, 2));
            am = fmaxf(am, __shfl_xor(am, 4));
            am = fmaxf(am, __shfl_xor(am, 8));
            const int rl = r0 + tile * 16 + q * 4 + r;
            const float thr = am - (0.0078125f * sqrtf(norm2L[rl] * en2) + 5e-5f);
            const float w1 = tile ? v1b[r] : v1a[r];
            const float w2 = tile ? v2b[r] : v2a[r];
            const float w3 = tile ? v3b[r] : v3a[r];
            const int   j1 = tile ? i1b[r] : i1a[r];
            const int   j2 = tile ? i2b[r] : i2a[r];
            if (w1 >= thr) { const int p = atomicAdd(&cntL[rl], 1);
                             if (p < CAPL) candL[rl][p] = j1; }
            if (w2 >= thr) { const int p = atomicAdd(&cntL[rl], 1);
                             if (p < CAPL) candL[rl][p] = j2; }
            if (w3 >= thr) atomicAdd(&cntL[rl], 64);   // poison: force full scan
        }
    }
    __syncthreads();

    // finalize single-candidate rows (+histogram); enqueue multi/overflow rows
    int my = -1, my2 = -1, c = 0;
    if (t < 256) {
        c = cntL[t];
        if (c == 1) {
            const int code = candL[t][0];
            out_ind[rowb + t] = (float)code;
            atomicAdd(bins_i + code, 1);
        }
        else if (c <= CAPL)   my  = atomicAdd(&mcount, 1);
        else                  my2 = atomicAdd(&mcount2, 1);
    }
    __syncthreads();
    if (t == 0) { mbase = atomicAdd(gcount, mcount); mbase2 = atomicAdd(gcount2, mcount2); }
    __syncthreads();
    if (my >= 0) {
        const int row = rowb + t;
        wl[mbase + my] = row;
        cntg[row] = c;
        #pragma unroll
        for (int j = 0; j < CAPL; ++j)
            if (j < c) candg[row * 8 + j] = candL[t][j];
    }
    if (my2 >= 0) wl2[mbase2 + my2] = rowb + t;
#undef STAGEQ
#undef CHUNKS
}

// ---- fused re-rank: thread-per-row (2..6 cands) + coalesced overflow scan ----
__global__ __launch_bounds__(256) void vq_rerank(
    const float* __restrict__ x, const float* __restrict__ embed,
    const float* __restrict__ e2f, const int* __restrict__ wl,
    const int* __restrict__ gcount, const int* __restrict__ cntg,
    const int* __restrict__ candg, const int* __restrict__ wl2,
    const int* __restrict__ gcount2, float* __restrict__ out_ind,
    int* __restrict__ bins_i)
{
    const int t = threadIdx.x;
    const int n = *gcount;
    for (int i = blockIdx.x * 256 + t; i < n; i += gridDim.x * 256) {
        const int row = wl[i];
        float xv[DDIM];
        {
            const float4* xp = reinterpret_cast<const float4*>(x + (size_t)row * DDIM);
            float4 xq[16];
            #pragma unroll
            for (int qq = 0; qq < 16; ++qq) xq[qq] = xp[qq];   // independent loads
            #pragma unroll
            for (int qq = 0; qq < 16; ++qq) {
                xv[qq*4+0] = xq[qq].x; xv[qq*4+1] = xq[qq].y;
                xv[qq*4+2] = xq[qq].z; xv[qq*4+3] = xq[qq].w;
            }
        }
        float x2 = 0.f;
        #pragma unroll
        for (int d = 0; d < DDIM; ++d) x2 = fmaf(xv[d], xv[d], x2);

        const int c = cntg[row];
        float bv = 3.4e38f; int bk = 0x7fffffff;
        for (int ci = 0; ci < c; ++ci) {
            const int k = candg[row * 8 + ci];
            const float4* ep = reinterpret_cast<const float4*>(embed + (size_t)k * DDIM);
            float dot = 0.f;
            #pragma unroll
            for (int qq = 0; qq < 16; ++qq) {
                const float4 e4 = ep[qq];
                dot = fmaf(xv[qq*4+0], e4.x, dot);
                dot = fmaf(xv[qq*4+1], e4.y, dot);
                dot = fmaf(xv[qq*4+2], e4.z, dot);
                dot = fmaf(xv[qq*4+3], e4.w, dot);
            }
            const float dist = (x2 - 2.0f * dot) + e2f[k];
            if (dist < bv || (dist == bv && k < bk)) { bv = dist; bk = k; }
        }
        out_ind[row] = (float)bk;
        atomicAdd(bins_i + bk, 1);
    }

    // overflow rows: one WAVE per row, lane = dim (coalesced), 4 codes/iter
    const int lane = t & 63;
    const int gw   = (blockIdx.x * 256 + t) >> 6;
    const int nw   = (gridDim.x * 256) >> 6;
    const int n2   = *gcount2;
    for (int e = gw; e < n2; e += nw) {
        const int row = wl2[e];
        const float xv = x[(size_t)row * DDIM + lane];
        float x2 = xv * xv;
        #pragma unroll
        for (int s = 1; s < 64; s <<= 1) x2 += __shfl_xor(x2, s);

        float bv = 3.4e38f; int bk = 0x7fffffff;
        for (int k = 0; k < KCODES; k += 4) {
            float t0 = xv * embed[(size_t)(k + 0) * DDIM + lane];
            float t1 = xv * embed[(size_t)(k + 1) * DDIM + lane];
            float t2 = xv * embed[(size_t)(k + 2) * DDIM + lane];
            float t3 = xv * embed[(size_t)(k + 3) * DDIM + lane];
            #pragma unroll
            for (int s = 1; s < 64; s <<= 1) {
                t0 += __shfl_xor(t0, s); t1 += __shfl_xor(t1, s);
                t2 += __shfl_xor(t2, s); t3 += __shfl_xor(t3, s);
            }
            const float d0 = (x2 - 2.0f * t0) + e2f[k + 0];
            const float d1 = (x2 - 2.0f * t1) + e2f[k + 1];
            const float d2 = (x2 - 2.0f * t2) + e2f[k + 2];
            const float d3 = (x2 - 2.0f * t3) + e2f[k + 3];
            if (d0 < bv) { bv = d0; bk = k + 0; }
            if (d1 < bv) { bv = d1; bk = k + 1; }
            if (d2 < bv) { bv = d2; bk = k + 2; }
            if (d3 < bv) { bv = d3; bk = k + 3; }
        }
        if (lane == 0) { out_ind[row] = (float)bk; atomicAdd(bins_i + bk, 1); }
    }
}

// ---- exclusive prefix over bins -> cursor ----
__global__ __launch_bounds__(1024) void vq_prefix(
    const int* __restrict__ bins_i, int* __restrict__ cursor)
{
    __shared__ int s[KCODES];
    const int t = threadIdx.x;
    const int b = bins_i[t];
    s[t] = b;
    __syncthreads();
    for (int d = 1; d < KCODES; d <<= 1) {
        const int v = (t >= d) ? s[t - d] : 0;
        __syncthreads();
        s[t] += v;
        __syncthreads();
    }
    cursor[t] = s[t] - b;
}

// ---- scatter packed (code<<20)|row into code-sorted order ----
__global__ __launch_bounds__(256) void vq_scatter(
    const float* __restrict__ out_ind, int* __restrict__ cursor, int* __restrict__ sorted)
{
    const int row  = blockIdx.x * 256 + threadIdx.x;
    const int code = (int)out_ind[row];
    const int pos  = atomicAdd(cursor + code, 1);
    sorted[pos] = (code << 20) | row;
}

// ---- balanced segmented reduce: 64 positions per wave, boundary atomics ----
__global__ __launch_bounds__(256) void vq_reduce(
    const float* __restrict__ x, const int* __restrict__ sorted,
    float* __restrict__ esum)
{
    const int t = threadIdx.x, lane = t & 63, w = t >> 6;
    const int p0 = (blockIdx.x * 4 + w) * 64;     // this wave's 64 positions

    int cur = sorted[p0] >> 20;
    float acc = 0.f;
    #pragma unroll 4
    for (int i = 0; i < 64; i += 4) {
        const int4 e4 = *reinterpret_cast<const int4*>(sorted + p0 + i);
        const float v0 = x[(size_t)(e4.x & 0xFFFFF) * DDIM + lane];
        const float v1 = x[(size_t)(e4.y & 0xFFFFF) * DDIM + lane];
        const float v2 = x[(size_t)(e4.z & 0xFFFFF) * DDIM + lane];
        const float v3 = x[(size_t)(e4.w & 0xFFFFF) * DDIM + lane];
        const int c0 = e4.x >> 20, c1 = e4.y >> 20, c2 = e4.z >> 20, c3 = e4.w >> 20;
        if (c0 != cur) { unsafeAtomicAdd(esum + cur * DDIM + lane, acc); acc = 0.f; cur = c0; }
        acc += v0;
        if (c1 != cur) { unsafeAtomicAdd(esum + cur * DDIM + lane, acc); acc = 0.f; cur = c1; }
        acc += v1;
        if (c2 != cur) { unsafeAtomicAdd(esum + cur * DDIM + lane, acc); acc = 0.f; cur = c2; }
        acc += v2;
        if (c3 != cur) { unsafeAtomicAdd(esum + cur * DDIM + lane, acc); acc = 0.f; cur = c3; }
        acc += v3;
    }
    unsafeAtomicAdd(esum + cur * DDIM + lane, acc);
}

// ---- finalize: EMA + Laplace smoothing ----
__global__ __launch_bounds__(1024) void vq_finalize(
    const float* __restrict__ cluster_size, const float* __restrict__ embed_avg,
    const int* __restrict__ bins_i, float* __restrict__ out_cs,
    float* __restrict__ out_eavg, float* __restrict__ out_enorm)
{
    __shared__ float red[KCODES];
    __shared__ float css[KCODES];
    const int t = threadIdx.x;

    const float csn = cluster_size[t] * 0.1f + (float)bins_i[t] * 0.9f;
    red[t] = csn;
    __syncthreads();
    for (int s = 512; s > 0; s >>= 1) {
        if (t < s) red[t] += red[t + s];
        __syncthreads();
    }
    const float n = red[0];
    out_cs[t] = csn;
    css[t] = (csn + 1e-5f) / (n + (float)(KCODES * 1e-5)) * n;
    __syncthreads();

    #pragma unroll
    for (int i = 0; i < 16; ++i) {
        const int f4 = t + i * 1024;
        const int k  = f4 >> 4;
        const float4 ea = reinterpret_cast<const float4*>(embed_avg)[f4];
        const float4 su = reinterpret_cast<const float4*>(out_eavg)[f4];
        const float  cc = css[k];
        float4 ean, en;
        ean.x = ea.x * 0.1f + su.x * 0.9f; en.x = ean.x / cc;
        ean.y = ea.y * 0.1f + su.y * 0.9f; en.y = ean.y / cc;
        ean.z = ea.z * 0.1f + su.z * 0.9f; en.z = ean.z / cc;
        ean.w = ea.w * 0.1f + su.w * 0.9f; en.w = ean.w / cc;
        reinterpret_cast<float4*>(out_eavg)[f4]  = ean;
        reinterpret_cast<float4*>(out_enorm)[f4] = en;
    }
}

// ---- quantize gather (runs last; out_q region doubles as scratch before) ----
__global__ __launch_bounds__(256) void vq_quant(
    const float* __restrict__ out_ind, const float* __restrict__ embed,
    float* __restrict__ out_q)
{
    __shared__ int inds[256];
    const int t = threadIdx.x;
    const int row0 = blockIdx.x * 256;
    inds[t] = (int)out_ind[row0 + t];
    __syncthreads();
    #pragma unroll
    for (int i = 0; i < 16; ++i) {
        const int f = t + i * 256;
        const int r = f >> 4, dq = f & 15;
        const int code = inds[r];
        const float4 ev = *reinterpret_cast<const float4*>(
            embed + (size_t)code * DDIM + dq * 4);
        *reinterpret_cast<float4*>(out_q + (size_t)(row0 + r) * DDIM + dq * 4) = ev;
    }
}

extern "C" void kernel_launch(void* const* d_in, const int* in_sizes, int n_in,
                              void* d_out, int out_size, void* d_ws, size_t ws_size,
                              hipStream_t stream)
{
    const float* x            = (const float*)d_in[0];
    const float* embed        = (const float*)d_in[1];
    const float* cluster_size = (const float*)d_in[2];
    const float* embed_avg    = (const float*)d_in[3];

    float* out      = (float*)d_out;
    float* out_q    = out;                                   // N*D (scratch until vq_quant)
    float* out_ind  = out_q + (size_t)NROWS * DDIM;          // N
    float* out_cs   = out_ind + NROWS;                       // K
    float* out_eavg = out_cs + KCODES;                       // K*D (embed_sum accum, then EMA)
    float* out_en   = out_eavg + (size_t)KCODES * DDIM;      // K*D (eb/e2f scratch, then enorm)

    unsigned short* eb = (unsigned short*)out_en;            // K*D bf16 = 128 KB (pre-swizzled)
    float* e2f = out_en + 32768;                             // K floats

    int* S      = (int*)out_q;                               // scratch inside out_q
    int* candg  = S;                                         // N*8
    int* cntg   = S + 2097152;                               // N
    int* wl     = cntg + 262144;                             // N
    int* wl2    = wl + 262144;                               // N
    int* sorted = wl2 + 262144;                              // N
    int* bins_i = sorted + 262144;                           // K
    int* gcount = bins_i + KCODES;                           // 1
    int* gcount2= gcount + 1;                                // 1
    float* enmax2 = (float*)(gcount2 + 1);                   // 1
    int* cursor = gcount2 + 2;                               // K

    hipMemsetAsync(bins_i, 0, (KCODES + 3) * sizeof(int), stream);
    hipMemsetAsync(out_eavg, 0, (size_t)KCODES * DDIM * sizeof(float), stream);

    vq_prep    <<<KCODES / 256, 256, 0, stream>>>(embed, eb, e2f, enmax2);
    vq_phaseA  <<<NROWS / 256, 512, 0, stream>>>(x, eb, e2f, enmax2, out_ind,
                                                 candg, cntg, wl, gcount,
                                                 wl2, gcount2, bins_i);
    vq_rerank  <<<512, 256, 0, stream>>>(x, embed, e2f, wl, gcount, cntg, candg,
                                         wl2, gcount2, out_ind, bins_i);
    vq_prefix  <<<1, 1024, 0, stream>>>(bins_i, cursor);
    vq_scatter <<<NROWS / 256, 256, 0, stream>>>(out_ind, cursor, sorted);
    vq_reduce  <<<NROWS / 256, 256, 0, stream>>>(x, sorted, out_eavg);
    vq_finalize<<<1, 1024, 0, stream>>>(cluster_size, embed_avg, bins_i,
                                        out_cs, out_eavg, out_en);
    vq_quant   <<<NROWS / 256, 256, 0, stream>>>(out_ind, embed, out_q);
}